// Round 14
// baseline (6537.408 us; speedup 1.0000x reference)
//
#include <hip/hip_runtime.h>
#include <hip/hip_bf16.h>
#include <cfloat>

// FPS matching the np reference bit-exactly (R7: PASS, absmax 0).
// FROZEN per-point arithmetic: dx=px-cx; y2=dy*dy; inner=fma(dx,dx,y2);
// d=fma(dz,dz,inner); nd=fminf(dist,d); winner=(max value, smallest index).
// R14: R13 showed dist stays in regs but px/py/pz get REMATERIALIZED from
// global every step (~196KB/CU/step L1 traffic = ~3000cy = the bottleneck).
// Fix: xy planes in LDS (128KB, ds_read_b64, bit-preserved), z+dist in regs
// (~79 live <= the 88 the allocator grants at 512 thr -> nothing to spill).

#define FPS_THREADS 512

#define REP32(M) M(0) M(1) M(2) M(3) M(4) M(5) M(6) M(7) \
                 M(8) M(9) M(10) M(11) M(12) M(13) M(14) M(15) \
                 M(16) M(17) M(18) M(19) M(20) M(21) M(22) M(23) \
                 M(24) M(25) M(26) M(27) M(28) M(29) M(30) M(31)

__global__ __launch_bounds__(FPS_THREADS, 2)
void fps_kernel(const float* __restrict__ xyz, int* __restrict__ out_idx,
                int N, int S) {
#pragma clang fp contract(off)
  const int b = blockIdx.x;
  const int t = threadIdx.x;
  const float* xb = xyz + (size_t)b * N * 3;

  __shared__ float2 s_xy[16384];                 // 128 KB: x,y planes
  __shared__ unsigned long long s_k[2][FPS_THREADS / 64];

#define DECLP(k) float pz##k, ds##k;
  REP32(DECLP)

  // one-time stage: x,y -> LDS (bit-exact), z+dist -> registers
#define LOADP(k) { int p = (k) * FPS_THREADS + t;               \
    s_xy[p] = make_float2(xb[(size_t)p * 3 + 0],                \
                          xb[(size_t)p * 3 + 1]);               \
    pz##k = xb[(size_t)p * 3 + 2];                              \
    ds##k = FLT_MAX; }
  REP32(LOADP)

  const int wave = t >> 6;
  const int lane = t & 63;
  const unsigned invt = 0xFFFFFFFFu - (unsigned)t;
  int farthest = 0;

  __syncthreads();  // s_xy visible

  for (int s = 0; s < S; ++s) {
    if (t == 0) out_idx[(size_t)b * S + s] = farthest;

    // centroid: uniform index -> LDS broadcast for x,y; scalar global for z
    int f = __builtin_amdgcn_readfirstlane(farthest);
    float cz = xb[(size_t)f * 3 + 2];
    float2 cxy = s_xy[f];
    float cx = cxy.x, cy = cxy.y;

    float bestv = -1.0f;
    int bestk = 0;   // k fits inline constant in v_cndmask

    // FROZEN reference arithmetic (LLVM DAG contraction form):
#define STEPP(k) {                                               \
    float2 xy = s_xy[(k) * FPS_THREADS + t];                     \
    float dx = xy.x - cx;                                        \
    float dy = xy.y - cy;                                        \
    float dz = pz##k - cz;                                       \
    float y2 = dy * dy;                                          \
    float inner = __builtin_fmaf(dx, dx, y2);                    \
    float dd = __builtin_fmaf(dz, dz, inner);                    \
    float nd = fminf(ds##k, dd);                                 \
    ds##k = nd;                                                  \
    if (nd > bestv) { bestv = nd; bestk = (k); } }
    REP32(STEPP)

    // pack once: (value bits << 32) | inverted original index
    unsigned bestinv = invt - (unsigned)(bestk * FPS_THREADS);
    unsigned long long bestkkey =
        ((unsigned long long)__float_as_uint(bestv) << 32) |
        (unsigned long long)bestinv;

    // wave butterfly max over u64 keys (dist >= 0 => key order is
    // (value, then smaller original index))
#pragma unroll
    for (int off = 32; off > 0; off >>= 1) {
      unsigned long long ok = __shfl_xor(bestkkey, off, 64);
      if (ok > bestkkey) bestkkey = ok;
    }

    // single barrier per step: parity double-buffer
    const int par = s & 1;
    if (lane == 0) s_k[par][wave] = bestkkey;
    __syncthreads();

    unsigned long long bk = s_k[par][0];
#pragma unroll
    for (int w = 1; w < FPS_THREADS / 64; ++w) {
      unsigned long long ok = s_k[par][w];
      if (ok > bk) bk = ok;
    }
    farthest = (int)(0xFFFFFFFFu - (unsigned)(bk & 0xFFFFFFFFu));
  }
}

// Gather: out = [ xyz[b][idx[b][s]][c] (B*S*3) , feat[b][idx[b][s]][:] (B*S*C) ]
__global__ void gather_kernel(const float* __restrict__ xyz,
                              const float* __restrict__ feat,
                              const int* __restrict__ idx,
                              float* __restrict__ out,
                              int B, int N, int S, int C) {
  const int c4pr = C >> 2;          // float4s per feat row
  const int nf4 = B * S * c4pr;     // total float4s of feat output
  int tid = blockIdx.x * blockDim.x + threadIdx.x;
  if (tid < nf4) {
    int c4 = tid % c4pr;
    int bs = tid / c4pr;
    int s = bs % S, b = bs / S;
    int p = idx[b * S + s];
    const float4* src = (const float4*)(feat + ((size_t)b * N + p) * C);
    float4* dst = (float4*)(out + (size_t)B * S * 3 + ((size_t)bs) * C);
    dst[c4] = src[c4];
  } else {
    int t2 = tid - nf4;
    int nxyz = B * S * 3;
    if (t2 < nxyz) {
      int c = t2 % 3;
      int bs = t2 / 3;
      int s = bs % S, b = bs / S;
      int p = idx[b * S + s];
      out[t2] = xyz[((size_t)b * N + p) * 3 + c];
    }
  }
}

extern "C" void kernel_launch(void* const* d_in, const int* in_sizes, int n_in,
                              void* d_out, int out_size, void* d_ws, size_t ws_size,
                              hipStream_t stream) {
  const float* xyz = (const float*)d_in[0];
  const float* feat = (const float*)d_in[1];
  float* out = (float*)d_out;

  const int B = 32;
  const int N = in_sizes[0] / (B * 3);        // 16384
  const int C = in_sizes[1] / (B * N);        // 128
  const int S = N / 4;                        // nsample = 0.25 * N = 4096

  int* d_idx = (int*)d_ws;  // B*S int32

  fps_kernel<<<B, FPS_THREADS, 0, stream>>>(xyz, d_idx, N, S);

  int total = B * S * (C >> 2) + B * S * 3;
  int blocks = (total + 255) / 256;
  gather_kernel<<<blocks, 256, 0, stream>>>(xyz, feat, d_idx, out, B, N, S, C);
}

// Round 15
// 6153.639 us; speedup vs baseline: 1.0624x; 1.0624x over previous
//
#include <hip/hip_runtime.h>
#include <hip/hip_bf16.h>
#include <cfloat>

// FPS matching the np reference bit-exactly (R7: PASS, absmax 0).
// FROZEN per-point arithmetic: dx=px-cx; y2=dy*dy; inner=fma(dx,dx,y2);
// d=fma(dz,dz,inner); nd=fminf(dist,d); winner=(max value, smallest index).
// R15: R13 had a 256-VGPR budget but the allocator kept only 88 and
// REMATERIALIZED ~60-90 coord loads per thread per step (~120KB/CU/step of
// L1/L2 traffic ~= 2100cy = the measured gap). asm "+v" pins make the loaded
// values opaque asm results -> remat impossible; with budget available the
// allocator must keep them register-resident. (R10's pin failed only because
// 1024thr pinned the budget tier at 64.)

#define FPS_THREADS 512

#define REP32(M) M(0) M(1) M(2) M(3) M(4) M(5) M(6) M(7) \
                 M(8) M(9) M(10) M(11) M(12) M(13) M(14) M(15) \
                 M(16) M(17) M(18) M(19) M(20) M(21) M(22) M(23) \
                 M(24) M(25) M(26) M(27) M(28) M(29) M(30) M(31)

__global__ __launch_bounds__(FPS_THREADS, 2)
void fps_kernel(const float* __restrict__ xyz, int* __restrict__ out_idx,
                int N, int S) {
#pragma clang fp contract(off)
  const int b = blockIdx.x;
  const int t = threadIdx.x;
  const float* xb = xyz + (size_t)b * N * 3;

#define DECLP(k) float px##k, py##k, pz##k, ds##k;
  REP32(DECLP)

#define LOADP(k) { int p = (k) * FPS_THREADS + t;      \
    px##k = xb[(size_t)p * 3 + 0];                     \
    py##k = xb[(size_t)p * 3 + 1];                     \
    pz##k = xb[(size_t)p * 3 + 2];                     \
    ds##k = FLT_MAX;                                   \
    asm volatile("" : "+v"(px##k), "+v"(py##k), "+v"(pz##k)); }
  REP32(LOADP)

  __shared__ unsigned long long s_k[2][FPS_THREADS / 64];

  const int wave = t >> 6;
  const int lane = t & 63;
  const unsigned invt = 0xFFFFFFFFu - (unsigned)t;
  int farthest = 0;

  for (int s = 0; s < S; ++s) {
    if (t == 0) out_idx[(size_t)b * S + s] = farthest;

    // centroid: block-uniform index -> scalar loads (L2-resident)
    int f = __builtin_amdgcn_readfirstlane(farthest);
    float cx = xb[(size_t)f * 3 + 0];
    float cy = xb[(size_t)f * 3 + 1];
    float cz = xb[(size_t)f * 3 + 2];

    float bestv = -1.0f;
    int bestk = 0;   // k fits inline constant in v_cndmask

    // FROZEN reference arithmetic (LLVM DAG contraction form):
#define STEPP(k) {                                               \
    float dx = px##k - cx;                                       \
    float dy = py##k - cy;                                       \
    float dz = pz##k - cz;                                       \
    float y2 = dy * dy;                                          \
    float inner = __builtin_fmaf(dx, dx, y2);                    \
    float dd = __builtin_fmaf(dz, dz, inner);                    \
    float nd = fminf(ds##k, dd);                                 \
    ds##k = nd;                                                  \
    if (nd > bestv) { bestv = nd; bestk = (k); } }
    REP32(STEPP)

    // inverted index once per step: inv = (0xFFFFFFFF - t) - k*512
    unsigned bestinv = invt - (unsigned)(bestk * FPS_THREADS);
    unsigned long long bestkkey =
        ((unsigned long long)__float_as_uint(bestv) << 32) |
        (unsigned long long)bestinv;

    // wave-level butterfly max over packed keys (dist >= 0 =>
    // u64 max == (max value, then smallest original index))
#pragma unroll
    for (int off = 32; off > 0; off >>= 1) {
      unsigned long long ok = __shfl_xor(bestkkey, off, 64);
      if (ok > bestkkey) bestkkey = ok;
    }

    // single barrier per step: parity double-buffer
    const int par = s & 1;
    if (lane == 0) s_k[par][wave] = bestkkey;
    __syncthreads();

    unsigned long long bk = s_k[par][0];
#pragma unroll
    for (int w = 1; w < FPS_THREADS / 64; ++w) {
      unsigned long long ok = s_k[par][w];
      if (ok > bk) bk = ok;
    }
    farthest = (int)(0xFFFFFFFFu - (unsigned)(bk & 0xFFFFFFFFu));
  }
}

// Gather: out = [ xyz[b][idx[b][s]][c] (B*S*3) , feat[b][idx[b][s]][:] (B*S*C) ]
__global__ void gather_kernel(const float* __restrict__ xyz,
                              const float* __restrict__ feat,
                              const int* __restrict__ idx,
                              float* __restrict__ out,
                              int B, int N, int S, int C) {
  const int c4pr = C >> 2;          // float4s per feat row
  const int nf4 = B * S * c4pr;     // total float4s of feat output
  int tid = blockIdx.x * blockDim.x + threadIdx.x;
  if (tid < nf4) {
    int c4 = tid % c4pr;
    int bs = tid / c4pr;
    int s = bs % S, b = bs / S;
    int p = idx[b * S + s];
    const float4* src = (const float4*)(feat + ((size_t)b * N + p) * C);
    float4* dst = (float4*)(out + (size_t)B * S * 3 + ((size_t)bs) * C);
    dst[c4] = src[c4];
  } else {
    int t2 = tid - nf4;
    int nxyz = B * S * 3;
    if (t2 < nxyz) {
      int c = t2 % 3;
      int bs = t2 / 3;
      int s = bs % S, b = bs / S;
      int p = idx[b * S + s];
      out[t2] = xyz[((size_t)b * N + p) * 3 + c];
    }
  }
}

extern "C" void kernel_launch(void* const* d_in, const int* in_sizes, int n_in,
                              void* d_out, int out_size, void* d_ws, size_t ws_size,
                              hipStream_t stream) {
  const float* xyz = (const float*)d_in[0];
  const float* feat = (const float*)d_in[1];
  float* out = (float*)d_out;

  const int B = 32;
  const int N = in_sizes[0] / (B * 3);        // 16384
  const int C = in_sizes[1] / (B * N);        // 128
  const int S = N / 4;                        // nsample = 0.25 * N = 4096

  int* d_idx = (int*)d_ws;  // B*S int32

  fps_kernel<<<B, FPS_THREADS, 0, stream>>>(xyz, d_idx, N, S);

  int total = B * S * (C >> 2) + B * S * 3;
  int blocks = (total + 255) / 256;
  gather_kernel<<<blocks, 256, 0, stream>>>(xyz, feat, d_idx, out, B, N, S, C);
}